// Round 1
// baseline (468.062 us; speedup 1.0000x reference)
//
#include <hip/hip_runtime.h>
#include <stdint.h>
#include <cmath>

#define BATCH 4
#define SEQ   2048
#define DM    1024
#define NH    16
#define HDIM  64
#define MROWS (BATCH*SEQ)   // 8192

typedef __attribute__((ext_vector_type(8))) __bf16 bf16x8;
typedef __attribute__((ext_vector_type(8))) unsigned short u16x8;
typedef __attribute__((ext_vector_type(4))) float f32x4;

__device__ __forceinline__ unsigned short f2bf(float f) {
  unsigned u = __float_as_uint(f);
  u = (u + 0x7FFFu + ((u >> 16) & 1u)) >> 16;   // RNE
  return (unsigned short)u;
}

__device__ __forceinline__ f32x4 mfma_bf16(bf16x8 a, bf16x8 b, f32x4 c) {
  return __builtin_amdgcn_mfma_f32_16x16x32_bf16(a, b, c, 0, 0, 0);
}

typedef const __attribute__((address_space(1))) unsigned int* as1_u32p;
typedef __attribute__((address_space(3))) unsigned int* as3_u32p;

// 16B direct global->LDS. LDS dest: wave-uniform base + lane*16. Global src: per-lane.
__device__ __forceinline__ void gload16(const void* g, void* l) {
  __builtin_amdgcn_global_load_lds((as1_u32p)g, (as3_u32p)l, 16, 0, 0);
}

// ---------------- fp32 -> bf16 convert ----------------
__global__ void cvt_f32_bf16(const float* __restrict__ src,
                             unsigned short* __restrict__ dst, int n4) {
  int i = blockIdx.x * blockDim.x + threadIdx.x;
  int stride = gridDim.x * blockDim.x;
  for (; i < n4; i += stride) {
    float4 v = ((const float4*)src)[i];
    ushort4 o;
    o.x = f2bf(v.x); o.y = f2bf(v.y); o.z = f2bf(v.z); o.w = f2bf(v.w);
    ((ushort4*)dst)[i] = o;
  }
}

// ---------------- shared GEMM mainloop: C(128x128) = A(128,K) * B(128,K)^T ----------------
// A,B bf16 row-major with row stride DM. LDS tiles 128x64 bf16, 128B rows,
// XOR-swizzled: LDS[row][x] = G[row][x ^ ((row&7)<<4)] (byte offsets within row).
__device__ __forceinline__ void gemm_tile_mainloop(
    const unsigned short* __restrict__ A, const unsigned short* __restrict__ Bw,
    int rowBase, int colBase,
    unsigned short* As, unsigned short* Bs,
    f32x4 acc[4][4], int tid)
{
  const int wid = tid >> 6, lane = tid & 63;
  const int wm = wid >> 1, wn = wid & 1;
  const unsigned short* Atile = A + (size_t)rowBase * DM;
  const unsigned short* Btile = Bw + (size_t)colBase * DM;

  for (int k0 = 0; k0 < DM; k0 += 64) {
    // stage A tile: 128 rows x 64 cols = 1024 16B-chunks, 4 issues of 256
#pragma unroll
    for (int j = 0; j < 4; ++j) {
      int c = j * 256 + tid;
      int row = c >> 3;
      int inB = (c & 7) * 16;
      int srcE = row * DM + k0 + ((inB ^ ((row & 7) << 4)) >> 1);
      gload16(Atile + srcE, As + (size_t)(j * 256 + wid * 64) * 8);
    }
#pragma unroll
    for (int j = 0; j < 4; ++j) {
      int c = j * 256 + tid;
      int row = c >> 3;
      int inB = (c & 7) * 16;
      int srcE = row * DM + k0 + ((inB ^ ((row & 7) << 4)) >> 1);
      gload16(Btile + srcE, Bs + (size_t)(j * 256 + wid * 64) * 8);
    }
    __syncthreads();   // drains vmcnt(0) -> gload_lds complete

#pragma unroll
    for (int s2 = 0; s2 < 2; ++s2) {
      bf16x8 af[4], bf[4];
#pragma unroll
      for (int m = 0; m < 4; ++m) {
        int row = wm * 64 + m * 16 + (lane & 15);
        int off = row * 128 + ((s2 * 64 + ((lane >> 4) * 16)) ^ ((row & 7) << 4));
        af[m] = *(const bf16x8*)((const char*)As + off);
      }
#pragma unroll
      for (int n = 0; n < 4; ++n) {
        int row = wn * 64 + n * 16 + (lane & 15);
        int off = row * 128 + ((s2 * 64 + ((lane >> 4) * 16)) ^ ((row & 7) << 4));
        bf[n] = *(const bf16x8*)((const char*)Bs + off);
      }
#pragma unroll
      for (int m = 0; m < 4; ++m)
#pragma unroll
        for (int n = 0; n < 4; ++n)
          acc[m][n] = mfma_bf16(af[m], bf[n], acc[m][n]);
    }
    __syncthreads();
  }
}

// ---------------- QKV projection: writes Q/K/V in [B,H,S,HD] bf16 ----------------
__global__ __launch_bounds__(256, 2) void gemm_qkv(
    const unsigned short* __restrict__ xb,
    const unsigned short* __restrict__ Wqb, const unsigned short* __restrict__ Wkb,
    const unsigned short* __restrict__ Wvb,
    unsigned short* __restrict__ Qd, unsigned short* __restrict__ Kd,
    unsigned short* __restrict__ Vd)
{
  __shared__ unsigned short As[128 * 64];
  __shared__ unsigned short Bs[128 * 64];
  const int tid = threadIdx.x;
  const int z = blockIdx.z;
  const unsigned short* W = (z == 0) ? Wqb : (z == 1) ? Wkb : Wvb;
  unsigned short* dst = (z == 0) ? Qd : (z == 1) ? Kd : Vd;
  const int rowBase = blockIdx.x * 128, colBase = blockIdx.y * 128;

  f32x4 acc[4][4];
#pragma unroll
  for (int m = 0; m < 4; ++m)
#pragma unroll
    for (int n = 0; n < 4; ++n) acc[m][n] = (f32x4){0.f, 0.f, 0.f, 0.f};

  gemm_tile_mainloop(xb, W, rowBase, colBase, As, Bs, acc, tid);

  const int wid = tid >> 6, lane = tid & 63;
  const int wm = wid >> 1, wn = wid & 1;
#pragma unroll
  for (int m = 0; m < 4; ++m)
#pragma unroll
    for (int n = 0; n < 4; ++n)
#pragma unroll
      for (int r = 0; r < 4; ++r) {
        int grow = rowBase + wm * 64 + m * 16 + ((lane >> 4) * 4) + r;  // b*SEQ+s
        int gcol = colBase + wn * 64 + n * 16 + (lane & 15);            // h*64+hd
        int b = grow >> 11, s = grow & (SEQ - 1);
        int h = gcol >> 6, hd = gcol & 63;
        dst[(((size_t)(b * NH + h)) * SEQ + s) * HDIM + hd] = f2bf(acc[m][n][r]);
      }
}

// ---------------- output projection: out = ctx @ Wo^T + bo (fp32 out) ----------------
__global__ __launch_bounds__(256, 2) void gemm_out(
    const unsigned short* __restrict__ ctx, const unsigned short* __restrict__ Wob,
    const float* __restrict__ bo, float* __restrict__ out)
{
  __shared__ unsigned short As[128 * 64];
  __shared__ unsigned short Bs[128 * 64];
  const int tid = threadIdx.x;
  const int rowBase = blockIdx.x * 128, colBase = blockIdx.y * 128;

  f32x4 acc[4][4];
#pragma unroll
  for (int m = 0; m < 4; ++m)
#pragma unroll
    for (int n = 0; n < 4; ++n) acc[m][n] = (f32x4){0.f, 0.f, 0.f, 0.f};

  gemm_tile_mainloop(ctx, Wob, rowBase, colBase, As, Bs, acc, tid);

  const int wid = tid >> 6, lane = tid & 63;
  const int wm = wid >> 1, wn = wid & 1;
#pragma unroll
  for (int m = 0; m < 4; ++m)
#pragma unroll
    for (int n = 0; n < 4; ++n)
#pragma unroll
      for (int r = 0; r < 4; ++r) {
        int grow = rowBase + wm * 64 + m * 16 + ((lane >> 4) * 4) + r;
        int gcol = colBase + wn * 64 + n * 16 + (lane & 15);
        out[(size_t)grow * DM + gcol] = acc[m][n][r] + bo[gcol];
      }
}

// ---------------- causal flash attention ----------------
// grid (32 qblocks, 64 bh). 4 waves x 16 q-rows. KV tile = 64.
__global__ __launch_bounds__(256, 2) void attn_fwd(
    const unsigned short* __restrict__ Qg, const unsigned short* __restrict__ Kg,
    const unsigned short* __restrict__ Vg, unsigned short* __restrict__ ctx)
{
  __shared__ unsigned short Klds[64 * 64];      // swizzled rows of 128B
  __shared__ unsigned short Vt[64 * 72];        // V^T [d][key], pad 72 (stride 144B = 9*16B)
  __shared__ unsigned short Plds[4 * 16 * 72];  // per-wave P, pad 72

  const int tid = threadIdx.x, wid = tid >> 6, lane = tid & 63;
  const int qb = blockIdx.x, bh = blockIdx.y;
  const size_t base = (size_t)bh * SEQ * HDIM;
  const unsigned short* Qp = Qg + base;
  const unsigned short* Kp = Kg + base;
  const unsigned short* Vp = Vg + base;

  // Q fragments in registers: A[row=q(lane&15)][d=s2*32+(lane>>4)*8 ..+7]
  bf16x8 aq[2];
  {
    int qrow = qb * 64 + wid * 16 + (lane & 15);
#pragma unroll
    for (int s2 = 0; s2 < 2; ++s2)
      aq[s2] = *(const bf16x8*)(Qp + (size_t)qrow * HDIM + s2 * 32 + ((lane >> 4) * 8));
  }

  f32x4 o[4];
#pragma unroll
  for (int df = 0; df < 4; ++df) o[df] = (f32x4){0.f, 0.f, 0.f, 0.f};
  float m_run[4], l_run[4];
#pragma unroll
  for (int r = 0; r < 4; ++r) { m_run[r] = -INFINITY; l_run[r] = 0.f; }

  const int nt = qb + 1;
  for (int t = 0; t < nt; ++t) {
    const unsigned short* Kt = Kp + (size_t)t * 64 * HDIM;
    const unsigned short* Vtg = Vp + (size_t)t * 64 * HDIM;
    // stage K (64x64, swizzled like GEMM tiles): 512 chunks, 2 issues
#pragma unroll
    for (int j = 0; j < 2; ++j) {
      int c = j * 256 + tid;
      int row = c >> 3;
      int inB = (c & 7) * 16;
      gload16(Kt + row * HDIM + ((inB ^ ((row & 7) << 4)) >> 1),
              Klds + (size_t)(j * 256 + wid * 64) * 8);
    }
    // stage V transposed via regs: Vt[d][key]
#pragma unroll
    for (int j = 0; j < 2; ++j) {
      int c = j * 256 + tid;
      int key = c >> 3;
      int d0 = (c & 7) * 8;
      u16x8 v = *(const u16x8*)(Vtg + key * HDIM + d0);
#pragma unroll
      for (int e = 0; e < 8; ++e) Vt[(d0 + e) * 72 + key] = v[e];
    }
    __syncthreads();

    // QK^T: scores [16 q x 64 key] per wave
    f32x4 sc[4];
#pragma unroll
    for (int kf = 0; kf < 4; ++kf) {
      int row = kf * 16 + (lane & 15);
      const char* kb = (const char*)Klds + row * 128;
      bf16x8 b0 = *(const bf16x8*)(kb + ((((lane >> 4) * 16)) ^ ((row & 7) << 4)));
      bf16x8 b1 = *(const bf16x8*)(kb + ((64 + ((lane >> 4) * 16)) ^ ((row & 7) << 4)));
      f32x4 z = (f32x4){0.f, 0.f, 0.f, 0.f};
      z = mfma_bf16(aq[0], b0, z);
      z = mfma_bf16(aq[1], b1, z);
      sc[kf] = z;
    }
#pragma unroll
    for (int kf = 0; kf < 4; ++kf)
#pragma unroll
      for (int r = 0; r < 4; ++r) sc[kf][r] *= 0.125f;  // 1/sqrt(64)

    if (t == qb) {  // diagonal tile: causal mask (block-relative q,key)
#pragma unroll
      for (int kf = 0; kf < 4; ++kf) {
        int key = kf * 16 + (lane & 15);
#pragma unroll
        for (int r = 0; r < 4; ++r) {
          int q = wid * 16 + ((lane >> 4) * 4) + r;
          if (key > q) sc[kf][r] = -INFINITY;
        }
      }
    }

    // online softmax (rows live on (lane>>4) group; reduce over low 4 lane bits)
    float alpha[4];
#pragma unroll
    for (int r = 0; r < 4; ++r) {
      float v = fmaxf(fmaxf(sc[0][r], sc[1][r]), fmaxf(sc[2][r], sc[3][r]));
      v = fmaxf(v, __shfl_xor(v, 1, 64));
      v = fmaxf(v, __shfl_xor(v, 2, 64));
      v = fmaxf(v, __shfl_xor(v, 4, 64));
      v = fmaxf(v, __shfl_xor(v, 8, 64));
      float mn = fmaxf(m_run[r], v);
      alpha[r] = __expf(m_run[r] - mn);
      m_run[r] = mn;
    }
    float rs[4];
#pragma unroll
    for (int r = 0; r < 4; ++r) rs[r] = 0.f;
#pragma unroll
    for (int kf = 0; kf < 4; ++kf)
#pragma unroll
      for (int r = 0; r < 4; ++r) {
        float p = __expf(sc[kf][r] - m_run[r]);
        sc[kf][r] = p;
        rs[r] += p;
      }
#pragma unroll
    for (int r = 0; r < 4; ++r) {
      float v = rs[r];
      v += __shfl_xor(v, 1, 64);
      v += __shfl_xor(v, 2, 64);
      v += __shfl_xor(v, 4, 64);
      v += __shfl_xor(v, 8, 64);
      l_run[r] = l_run[r] * alpha[r] + v;
    }
#pragma unroll
    for (int df = 0; df < 4; ++df)
#pragma unroll
      for (int r = 0; r < 4; ++r) o[df][r] *= alpha[r];

    // P (score layout) -> per-wave LDS -> A-operand layout
    unsigned short* P = Plds + wid * (16 * 72);
#pragma unroll
    for (int kf = 0; kf < 4; ++kf)
#pragma unroll
      for (int r = 0; r < 4; ++r)
        P[(((lane >> 4) * 4) + r) * 72 + kf * 16 + (lane & 15)] = f2bf(sc[kf][r]);

    bf16x8 pa[2];
#pragma unroll
    for (int s2 = 0; s2 < 2; ++s2)
      pa[s2] = *(const bf16x8*)((const char*)P + (lane & 15) * 144 + s2 * 64 + ((lane >> 4) * 16));

    // PV: o[16 q x 64 d] += P[16 x 64] * V[64 x 64]
#pragma unroll
    for (int df = 0; df < 4; ++df) {
      const char* vb = (const char*)Vt + (df * 16 + (lane & 15)) * 144;
#pragma unroll
      for (int s2 = 0; s2 < 2; ++s2) {
        bf16x8 bv = *(const bf16x8*)(vb + s2 * 64 + ((lane >> 4) * 16));
        o[df] = mfma_bf16(pa[s2], bv, o[df]);
      }
    }
    __syncthreads();
  }

  // epilogue: normalize, write ctx in [B,S,D] bf16
  const int b = bh >> 4, h = bh & 15;
  float invl[4];
#pragma unroll
  for (int r = 0; r < 4; ++r) invl[r] = 1.0f / l_run[r];
#pragma unroll
  for (int df = 0; df < 4; ++df)
#pragma unroll
    for (int r = 0; r < 4; ++r) {
      int s = qb * 64 + wid * 16 + ((lane >> 4) * 4) + r;
      int col = h * 64 + df * 16 + (lane & 15);
      ctx[((size_t)(b * SEQ + s)) * DM + col] = f2bf(o[df][r] * invl[r]);
    }
}

// ---------------- launch ----------------
extern "C" void kernel_launch(void* const* d_in, const int* in_sizes, int n_in,
                              void* d_out, int out_size, void* d_ws, size_t ws_size,
                              hipStream_t stream)
{
  (void)in_sizes; (void)n_in; (void)out_size; (void)ws_size;
  const float* x  = (const float*)d_in[0];
  const float* Wq = (const float*)d_in[1];
  const float* Wk = (const float*)d_in[2];
  const float* Wv = (const float*)d_in[3];
  const float* Wo = (const float*)d_in[4];
  const float* bo = (const float*)d_in[5];
  float* out = (float*)d_out;

  char* ws = (char*)d_ws;
  unsigned short* xb  = (unsigned short*)(ws);                        // 16 MiB
  unsigned short* Wqb = (unsigned short*)(ws + (size_t)16 * 1048576); //  2 MiB
  unsigned short* Wkb = (unsigned short*)(ws + (size_t)18 * 1048576);
  unsigned short* Wvb = (unsigned short*)(ws + (size_t)20 * 1048576);
  unsigned short* Wob = (unsigned short*)(ws + (size_t)22 * 1048576);
  unsigned short* Qd  = (unsigned short*)(ws + (size_t)24 * 1048576); // 16 MiB [B,H,S,HD]
  unsigned short* Kd  = (unsigned short*)(ws + (size_t)40 * 1048576);
  unsigned short* Vd  = (unsigned short*)(ws + (size_t)56 * 1048576);
  unsigned short* ctx = (unsigned short*)(ws + (size_t)72 * 1048576); // 16 MiB [B,S,D]

  cvt_f32_bf16<<<2048, 256, 0, stream>>>(x,  xb,  MROWS * DM / 4);
  cvt_f32_bf16<<<256,  256, 0, stream>>>(Wq, Wqb, DM * DM / 4);
  cvt_f32_bf16<<<256,  256, 0, stream>>>(Wk, Wkb, DM * DM / 4);
  cvt_f32_bf16<<<256,  256, 0, stream>>>(Wv, Wvb, DM * DM / 4);
  cvt_f32_bf16<<<256,  256, 0, stream>>>(Wo, Wob, DM * DM / 4);

  gemm_qkv<<<dim3(MROWS / 128, DM / 128, 3), 256, 0, stream>>>(xb, Wqb, Wkb, Wvb, Qd, Kd, Vd);
  attn_fwd<<<dim3(SEQ / 64, BATCH * NH), 256, 0, stream>>>(Qd, Kd, Vd, ctx);
  gemm_out<<<dim3(MROWS / 128, DM / 128, 1), 256, 0, stream>>>(ctx, Wob, bo, out);
}

// Round 2
// 291.736 us; speedup vs baseline: 1.6044x; 1.6044x over previous
//
#include <hip/hip_runtime.h>
#include <stdint.h>
#include <cmath>

#define BATCH 4
#define SEQ   2048
#define DM    1024
#define NH    16
#define HDIM  64
#define MROWS (BATCH*SEQ)   // 8192

typedef __attribute__((ext_vector_type(8)))  __bf16 bf16x8;
typedef __attribute__((ext_vector_type(8)))  unsigned short u16x8;
typedef __attribute__((ext_vector_type(4)))  float f32x4;
typedef __attribute__((ext_vector_type(16))) float f32x16;
typedef __attribute__((ext_vector_type(4)))  unsigned int u32x4;

__device__ __forceinline__ unsigned short f2bf(float f) {
  unsigned u = __float_as_uint(f);
  u = (u + 0x7FFFu + ((u >> 16) & 1u)) >> 16;   // RNE
  return (unsigned short)u;
}

__device__ __forceinline__ f32x4 mfma_bf16(bf16x8 a, bf16x8 b, f32x4 c) {
  return __builtin_amdgcn_mfma_f32_16x16x32_bf16(a, b, c, 0, 0, 0);
}
__device__ __forceinline__ f32x16 mfma32(bf16x8 a, bf16x8 b, f32x16 c) {
  return __builtin_amdgcn_mfma_f32_32x32x16_bf16(a, b, c, 0, 0, 0);
}

__device__ __forceinline__ unsigned cvtpk(float lo, float hi) {
  unsigned r;
  asm("v_cvt_pk_bf16_f32 %0, %1, %2" : "=v"(r) : "v"(lo), "v"(hi));
  return r;
}
__device__ __forceinline__ void permswap(unsigned &a, unsigned &b) {
  asm volatile("v_permlane32_swap_b32 %0, %1" : "+v"(a), "+v"(b));
}
__device__ __forceinline__ f32x16 zero16() {
  f32x16 z;
#pragma unroll
  for (int i = 0; i < 16; ++i) z[i] = 0.f;
  return z;
}

typedef const __attribute__((address_space(1))) unsigned int* as1_u32p;
typedef __attribute__((address_space(3))) unsigned int* as3_u32p;

// 16B direct global->LDS. LDS dest: wave-uniform base + lane*16. Global src: per-lane.
__device__ __forceinline__ void gload16(const void* g, void* l) {
  __builtin_amdgcn_global_load_lds((as1_u32p)g, (as3_u32p)l, 16, 0, 0);
}

// ---------------- fp32 -> bf16 convert ----------------
__global__ void cvt_f32_bf16(const float* __restrict__ src,
                             unsigned short* __restrict__ dst, int n4) {
  int i = blockIdx.x * blockDim.x + threadIdx.x;
  int stride = gridDim.x * blockDim.x;
  for (; i < n4; i += stride) {
    float4 v = ((const float4*)src)[i];
    ushort4 o;
    o.x = f2bf(v.x); o.y = f2bf(v.y); o.z = f2bf(v.z); o.w = f2bf(v.w);
    ((ushort4*)dst)[i] = o;
  }
}

// ---------------- shared GEMM mainloop: C(128x128) = A(128,K) * B(128,K)^T ----------------
__device__ __forceinline__ void gemm_tile_mainloop(
    const unsigned short* __restrict__ A, const unsigned short* __restrict__ Bw,
    int rowBase, int colBase,
    unsigned short* As, unsigned short* Bs,
    f32x4 acc[4][4], int tid)
{
  const int wid = tid >> 6, lane = tid & 63;
  const int wm = wid >> 1, wn = wid & 1;
  const unsigned short* Atile = A + (size_t)rowBase * DM;
  const unsigned short* Btile = Bw + (size_t)colBase * DM;

  for (int k0 = 0; k0 < DM; k0 += 64) {
#pragma unroll
    for (int j = 0; j < 4; ++j) {
      int c = j * 256 + tid;
      int row = c >> 3;
      int inB = (c & 7) * 16;
      int srcE = row * DM + k0 + ((inB ^ ((row & 7) << 4)) >> 1);
      gload16(Atile + srcE, As + (size_t)(j * 256 + wid * 64) * 8);
    }
#pragma unroll
    for (int j = 0; j < 4; ++j) {
      int c = j * 256 + tid;
      int row = c >> 3;
      int inB = (c & 7) * 16;
      int srcE = row * DM + k0 + ((inB ^ ((row & 7) << 4)) >> 1);
      gload16(Btile + srcE, Bs + (size_t)(j * 256 + wid * 64) * 8);
    }
    __syncthreads();

#pragma unroll
    for (int s2 = 0; s2 < 2; ++s2) {
      bf16x8 af[4], bfv[4];
#pragma unroll
      for (int m = 0; m < 4; ++m) {
        int row = wm * 64 + m * 16 + (lane & 15);
        int off = row * 128 + ((s2 * 64 + ((lane >> 4) * 16)) ^ ((row & 7) << 4));
        af[m] = *(const bf16x8*)((const char*)As + off);
      }
#pragma unroll
      for (int n = 0; n < 4; ++n) {
        int row = wn * 64 + n * 16 + (lane & 15);
        int off = row * 128 + ((s2 * 64 + ((lane >> 4) * 16)) ^ ((row & 7) << 4));
        bfv[n] = *(const bf16x8*)((const char*)Bs + off);
      }
#pragma unroll
      for (int m = 0; m < 4; ++m)
#pragma unroll
        for (int n = 0; n < 4; ++n)
          acc[m][n] = mfma_bf16(af[m], bfv[n], acc[m][n]);
    }
    __syncthreads();
  }
}

// ---------------- QKV projection: writes Q/K/V in [B,H,S,HD] bf16 ----------------
__global__ __launch_bounds__(256, 2) void gemm_qkv(
    const unsigned short* __restrict__ xb,
    const unsigned short* __restrict__ Wqb, const unsigned short* __restrict__ Wkb,
    const unsigned short* __restrict__ Wvb,
    unsigned short* __restrict__ Qd, unsigned short* __restrict__ Kd,
    unsigned short* __restrict__ Vd)
{
  __shared__ unsigned short As[128 * 64];
  __shared__ unsigned short Bs[128 * 64];
  const int tid = threadIdx.x;
  const int z = blockIdx.z;
  const unsigned short* W = (z == 0) ? Wqb : (z == 1) ? Wkb : Wvb;
  unsigned short* dst = (z == 0) ? Qd : (z == 1) ? Kd : Vd;
  const int rowBase = blockIdx.x * 128, colBase = blockIdx.y * 128;

  f32x4 acc[4][4];
#pragma unroll
  for (int m = 0; m < 4; ++m)
#pragma unroll
    for (int n = 0; n < 4; ++n) acc[m][n] = (f32x4){0.f, 0.f, 0.f, 0.f};

  gemm_tile_mainloop(xb, W, rowBase, colBase, As, Bs, acc, tid);

  const int wid = tid >> 6, lane = tid & 63;
  const int wm = wid >> 1, wn = wid & 1;
#pragma unroll
  for (int m = 0; m < 4; ++m)
#pragma unroll
    for (int n = 0; n < 4; ++n)
#pragma unroll
      for (int r = 0; r < 4; ++r) {
        int grow = rowBase + wm * 64 + m * 16 + ((lane >> 4) * 4) + r;  // b*SEQ+s
        int gcol = colBase + wn * 64 + n * 16 + (lane & 15);            // h*64+hd
        int b = grow >> 11, s = grow & (SEQ - 1);
        int h = gcol >> 6, hd = gcol & 63;
        dst[(((size_t)(b * NH + h)) * SEQ + s) * HDIM + hd] = f2bf(acc[m][n][r]);
      }
}

// ---------------- output projection: out = ctx @ Wo^T + bo (fp32 out) ----------------
__global__ __launch_bounds__(256, 2) void gemm_out(
    const unsigned short* __restrict__ ctx, const unsigned short* __restrict__ Wob,
    const float* __restrict__ bo, float* __restrict__ out)
{
  __shared__ unsigned short As[128 * 64];
  __shared__ unsigned short Bs[128 * 64];
  const int tid = threadIdx.x;
  const int rowBase = blockIdx.x * 128, colBase = blockIdx.y * 128;

  f32x4 acc[4][4];
#pragma unroll
  for (int m = 0; m < 4; ++m)
#pragma unroll
    for (int n = 0; n < 4; ++n) acc[m][n] = (f32x4){0.f, 0.f, 0.f, 0.f};

  gemm_tile_mainloop(ctx, Wob, rowBase, colBase, As, Bs, acc, tid);

  const int wid = tid >> 6, lane = tid & 63;
  const int wm = wid >> 1, wn = wid & 1;
#pragma unroll
  for (int m = 0; m < 4; ++m)
#pragma unroll
    for (int n = 0; n < 4; ++n)
#pragma unroll
      for (int r = 0; r < 4; ++r) {
        int grow = rowBase + wm * 64 + m * 16 + ((lane >> 4) * 4) + r;
        int gcol = colBase + wn * 64 + n * 16 + (lane & 15);
        out[(size_t)grow * DM + gcol] = acc[m][n][r] + bo[gcol];
      }
}

// ---------------- V transpose: [B,H,S,HD] -> [B,H,HD,S] ----------------
__global__ void transpose_v(const unsigned short* __restrict__ Vd,
                            unsigned short* __restrict__ VT)
{
  __shared__ unsigned short tile[64 * 72];   // [s][d], pad 72 (144B rows, 16B aligned)
  const int tid = threadIdx.x;
  const int bh = blockIdx.y, s0 = blockIdx.x * 64;
  const unsigned short* src = Vd + (size_t)bh * SEQ * HDIM + (size_t)s0 * HDIM;
#pragma unroll
  for (int j = 0; j < 2; ++j) {
    int c = j * 256 + tid;
    int r = c >> 3, c0 = (c & 7) * 8;
    *(u16x8*)(tile + r * 72 + c0) = *(const u16x8*)(src + r * HDIM + c0);
  }
  __syncthreads();
  unsigned short* dst = VT + (size_t)bh * HDIM * SEQ + s0;
#pragma unroll
  for (int j = 0; j < 2; ++j) {
    int c = j * 256 + tid;
    int d = c >> 3, c0 = (c & 7) * 8;   // c0 = s offset within tile
    u16x8 v;
#pragma unroll
    for (int e = 0; e < 8; ++e) v[e] = tile[(c0 + e) * 72 + d];
    *(u16x8*)(dst + (size_t)d * SEQ + c0) = v;
  }
}

// ---------------- causal flash attention, swapped-QK^T 32x32 structure ----------------
// grid (16 qblocks, 64 bh), 4 warps x 32 q-rows, KV tile 64, dbuf K/V in LDS.
__global__ __launch_bounds__(256, 2) void attn_fwd2(
    const unsigned short* __restrict__ Qg, const unsigned short* __restrict__ Kg,
    const unsigned short* __restrict__ VTg, unsigned short* __restrict__ ctx)
{
  __shared__ unsigned short smem[16384];  // [0,8K): K dbuf, [8K,16K): V^T dbuf (u16 units)

  const int tid = threadIdx.x, wid = tid >> 6, lane = tid & 63;
  const int hi = lane >> 5, lq = lane & 31;
  const int qb = (int)gridDim.x - 1 - (int)blockIdx.x;   // big blocks first
  const int bh = blockIdx.y;
  const unsigned short* Qp = Qg  + (size_t)bh * SEQ * HDIM;
  const unsigned short* Kp = Kg  + (size_t)bh * SEQ * HDIM;
  const unsigned short* Vp = VTg + (size_t)bh * HDIM * SEQ;   // [d][s]
  const int qw0 = qb * 128 + wid * 32;       // warp's first q row

  // Q B-frags: lane q=lq, d = ks*16 + hi*8 + j  (scale folded into exp later)
  bf16x8 qf[4];
  {
    const unsigned short* qrow = Qp + (size_t)(qw0 + lq) * HDIM + hi * 8;
#pragma unroll
    for (int ks = 0; ks < 4; ++ks) qf[ks] = *(const bf16x8*)(qrow + ks * 16);
  }

  f32x16 o0 = zero16(), o1 = zero16();
  float m_run = -INFINITY, l_run = 0.f;

  const int nt = 2 * qb + 2;

  // ---- stage helpers (lambdas, wave-uniform LDS dest base) ----
  auto stageK = [&](int t, int buf) {
#pragma unroll
    for (int j = 0; j < 2; ++j) {
      int c = j * 256 + tid;
      int row = c >> 3, inB = (c & 7) * 16;
      gload16(Kp + (size_t)(t * 64 + row) * HDIM + ((inB ^ ((row & 7) << 4)) >> 1),
              smem + buf * 4096 + (size_t)(j * 256 + wid * 64) * 8);
    }
  };
  auto stageV = [&](int t, int buf) {
#pragma unroll
    for (int j = 0; j < 2; ++j) {
      int c = j * 256 + tid;
      int row = c >> 3, inB = (c & 7) * 16;   // row = d
      gload16(Vp + (size_t)row * SEQ + t * 64 + ((inB ^ ((row & 7) << 4)) >> 1),
              smem + 8192 + buf * 4096 + (size_t)(j * 256 + wid * 64) * 8);
    }
  };

  stageK(0, 0); stageV(0, 0);
  __syncthreads();

  for (int t = 0; t < nt; ++t) {
    const int cur = t & 1;
    if (t + 1 < nt) { stageK(t + 1, cur ^ 1); stageV(t + 1, cur ^ 1); }

    if (t * 64 <= qw0 + 31) {   // warp has at least one visible key in this tile
      // ---- QK^T: S^T[64 key][32 q], lane owns q=lq; keys split lane<->lane+32 ----
      const unsigned short* Kl = smem + cur * 4096;
      f32x16 s0 = zero16(), s1 = zero16();
#pragma unroll
      for (int ks = 0; ks < 4; ++ks) {
        int r0 = lq, r1 = lq + 32;
        int col = (ks * 32 + hi * 16);
        bf16x8 a0 = *(const bf16x8*)((const char*)Kl + r0 * 128 + (col ^ ((r0 & 7) << 4)));
        bf16x8 a1 = *(const bf16x8*)((const char*)Kl + r1 * 128 + (col ^ ((r1 & 7) << 4)));
        s0 = mfma32(a0, qf[ks], s0);
        s1 = mfma32(a1, qf[ks], s1);
      }

      // ---- causal mask (raw scores; scale folded into exp) ----
      if (t * 64 + 63 > qw0) {
        const int q = qw0 + lq;
        const int kb = t * 64 + 4 * hi;
#pragma unroll
        for (int r = 0; r < 16; ++r) {
          int k0 = kb + (r & 3) + 8 * (r >> 2);
          if (k0 > q)      s0[r] = -INFINITY;
          if (k0 + 32 > q) s1[r] = -INFINITY;
        }
      }

      // ---- online softmax, lane-local (32 regs) + 1 cross-half exchange ----
      float pmax = s0[0];
#pragma unroll
      for (int r = 1; r < 16; ++r) pmax = fmaxf(pmax, s0[r]);
#pragma unroll
      for (int r = 0; r < 16; ++r) pmax = fmaxf(pmax, s1[r]);
      pmax = fmaxf(pmax, __shfl_xor(pmax, 32, 64));

      if (!__all(pmax - m_run <= 64.0f)) {     // defer-max THR: e^(64*0.125)=e^8
        float mn = fmaxf(m_run, pmax);
        float alpha = __expf((m_run - mn) * 0.125f);
        l_run *= alpha;
#pragma unroll
        for (int r = 0; r < 16; ++r) { o0[r] *= alpha; o1[r] *= alpha; }
        m_run = mn;
      }

      float rsum = 0.f;
#pragma unroll
      for (int r = 0; r < 16; ++r) {
        s0[r] = __expf((s0[r] - m_run) * 0.125f); rsum += s0[r];
      }
#pragma unroll
      for (int r = 0; r < 16; ++r) {
        s1[r] = __expf((s1[r] - m_run) * 0.125f); rsum += s1[r];
      }
      rsum += __shfl_xor(rsum, 32, 64);
      l_run += rsum;

      // ---- P -> bf16 B-frags via cvt_pk + permlane32_swap (T12) ----
      bf16x8 pfr[4];
#pragma unroll
      for (int h2 = 0; h2 < 2; ++h2) {
        {
          unsigned va = cvtpk(s0[h2 * 8 + 0], s0[h2 * 8 + 1]);
          unsigned vb = cvtpk(s0[h2 * 8 + 4], s0[h2 * 8 + 5]);
          unsigned vc = cvtpk(s0[h2 * 8 + 2], s0[h2 * 8 + 3]);
          unsigned vd = cvtpk(s0[h2 * 8 + 6], s0[h2 * 8 + 7]);
          permswap(va, vb); permswap(vc, vd);
          u32x4 tt; tt.x = va; tt.y = vc; tt.z = vb; tt.w = vd;
          pfr[h2] = __builtin_bit_cast(bf16x8, tt);
        }
        {
          unsigned va = cvtpk(s1[h2 * 8 + 0], s1[h2 * 8 + 1]);
          unsigned vb = cvtpk(s1[h2 * 8 + 4], s1[h2 * 8 + 5]);
          unsigned vc = cvtpk(s1[h2 * 8 + 2], s1[h2 * 8 + 3]);
          unsigned vd = cvtpk(s1[h2 * 8 + 6], s1[h2 * 8 + 7]);
          permswap(va, vb); permswap(vc, vd);
          u32x4 tt; tt.x = va; tt.y = vc; tt.z = vb; tt.w = vd;
          pfr[2 + h2] = __builtin_bit_cast(bf16x8, tt);
        }
      }

      // ---- PV: O^T[64 d][32 q] += V^T * P^T ----
      const unsigned short* Vl = smem + 8192 + cur * 4096;
#pragma unroll
      for (int ks = 0; ks < 4; ++ks) {
        int r0 = lq, r1 = lq + 32;   // d rows
        int col = (ks * 32 + hi * 16);
        bf16x8 va0 = *(const bf16x8*)((const char*)Vl + r0 * 128 + (col ^ ((r0 & 7) << 4)));
        bf16x8 va1 = *(const bf16x8*)((const char*)Vl + r1 * 128 + (col ^ ((r1 & 7) << 4)));
        o0 = mfma32(va0, pfr[ks], o0);
        o1 = mfma32(va1, pfr[ks], o1);
      }
    }
    __syncthreads();
  }

  // ---- epilogue: normalize, bounce through LDS, coalesced store [B,S,D] ----
  const float invl = 1.0f / l_run;
  unsigned short* Ot = smem;            // [128 q][64 d] bf16, XOR-swizzled rows
  const int q = wid * 32 + lq;
#pragma unroll
  for (int r2 = 0; r2 < 16; r2 += 2) {
    int d = (r2 & 3) + 8 * (r2 >> 2) + 4 * hi;
    unsigned w0 = cvtpk(o0[r2] * invl, o0[r2 + 1] * invl);
    *(unsigned*)((char*)Ot + q * 128 + ((2 * d) ^ ((q & 7) << 4))) = w0;
    int d2 = d + 32;
    unsigned w1 = cvtpk(o1[r2] * invl, o1[r2 + 1] * invl);
    *(unsigned*)((char*)Ot + q * 128 + ((2 * d2) ^ ((q & 7) << 4))) = w1;
  }
  __syncthreads();

  const int b = bh >> 4, h = bh & 15;
#pragma unroll
  for (int i = 0; i < 4; ++i) {
    int idx = i * 256 + tid;
    int qq = idx >> 3, c16 = (idx & 7) * 8;
    bf16x8 v = *(const bf16x8*)((const char*)Ot + qq * 128 + ((2 * c16) ^ ((qq & 7) << 4)));
    *(bf16x8*)(ctx + ((size_t)(b * SEQ) + qb * 128 + qq) * DM + h * 64 + c16) = v;
  }
}

// ---------------- launch ----------------
extern "C" void kernel_launch(void* const* d_in, const int* in_sizes, int n_in,
                              void* d_out, int out_size, void* d_ws, size_t ws_size,
                              hipStream_t stream)
{
  (void)in_sizes; (void)n_in; (void)out_size; (void)ws_size;
  const float* x  = (const float*)d_in[0];
  const float* Wq = (const float*)d_in[1];
  const float* Wk = (const float*)d_in[2];
  const float* Wv = (const float*)d_in[3];
  const float* Wo = (const float*)d_in[4];
  const float* bo = (const float*)d_in[5];
  float* out = (float*)d_out;

  char* ws = (char*)d_ws;
  unsigned short* xb  = (unsigned short*)(ws);                        // 16 MiB (x bf16; reused as V^T)
  unsigned short* Wqb = (unsigned short*)(ws + (size_t)16 * 1048576);
  unsigned short* Wkb = (unsigned short*)(ws + (size_t)18 * 1048576);
  unsigned short* Wvb = (unsigned short*)(ws + (size_t)20 * 1048576);
  unsigned short* Wob = (unsigned short*)(ws + (size_t)22 * 1048576);
  unsigned short* Qd  = (unsigned short*)(ws + (size_t)24 * 1048576); // [B,H,S,HD]
  unsigned short* Kd  = (unsigned short*)(ws + (size_t)40 * 1048576);
  unsigned short* Vd  = (unsigned short*)(ws + (size_t)56 * 1048576);
  unsigned short* ctxb= (unsigned short*)(ws + (size_t)72 * 1048576); // [B,S,D]
  unsigned short* VT  = xb;                                           // [B,H,HD,S] (x dead after gemm_qkv)

  cvt_f32_bf16<<<2048, 256, 0, stream>>>(x,  xb,  MROWS * DM / 4);
  cvt_f32_bf16<<<256,  256, 0, stream>>>(Wq, Wqb, DM * DM / 4);
  cvt_f32_bf16<<<256,  256, 0, stream>>>(Wk, Wkb, DM * DM / 4);
  cvt_f32_bf16<<<256,  256, 0, stream>>>(Wv, Wvb, DM * DM / 4);
  cvt_f32_bf16<<<256,  256, 0, stream>>>(Wo, Wob, DM * DM / 4);

  gemm_qkv<<<dim3(MROWS / 128, DM / 128, 3), 256, 0, stream>>>(xb, Wqb, Wkb, Wvb, Qd, Kd, Vd);
  transpose_v<<<dim3(SEQ / 64, BATCH * NH), 256, 0, stream>>>(Vd, VT);
  attn_fwd2<<<dim3(SEQ / 128, BATCH * NH), 256, 0, stream>>>(Qd, Kd, VT, ctxb);
  gemm_out<<<dim3(MROWS / 128, DM / 128, 1), 256, 0, stream>>>(ctxb, Wob, bo, out);
}

// Round 4
// 242.288 us; speedup vs baseline: 1.9318x; 1.2041x over previous
//
#include <hip/hip_runtime.h>
#include <stdint.h>
#include <cmath>

#define BATCH 4
#define SEQ   2048
#define DM    1024
#define NH    16
#define HDIM  64
#define MROWS (BATCH*SEQ)   // 8192
#define NQB   16            // SEQ/128 q-blocks

typedef __attribute__((ext_vector_type(8)))  __bf16 bf16x8;
typedef __attribute__((ext_vector_type(8)))  unsigned short u16x8;
typedef __attribute__((ext_vector_type(4)))  float f32x4;
typedef __attribute__((ext_vector_type(16))) float f32x16;
typedef __attribute__((ext_vector_type(4)))  unsigned int u32x4;

__device__ __forceinline__ unsigned short f2bf(float f) {
  unsigned u = __float_as_uint(f);
  u = (u + 0x7FFFu + ((u >> 16) & 1u)) >> 16;   // RNE
  return (unsigned short)u;
}

__device__ __forceinline__ f32x4 mfma_bf16(bf16x8 a, bf16x8 b, f32x4 c) {
  return __builtin_amdgcn_mfma_f32_16x16x32_bf16(a, b, c, 0, 0, 0);
}
__device__ __forceinline__ f32x16 mfma32(bf16x8 a, bf16x8 b, f32x16 c) {
  return __builtin_amdgcn_mfma_f32_32x32x16_bf16(a, b, c, 0, 0, 0);
}

__device__ __forceinline__ unsigned cvtpk(float lo, float hi) {
  unsigned r;
  asm("v_cvt_pk_bf16_f32 %0, %1, %2" : "=v"(r) : "v"(lo), "v"(hi));
  return r;
}
__device__ __forceinline__ void permswap(unsigned &a, unsigned &b) {
  asm volatile("v_permlane32_swap_b32 %0, %1" : "+v"(a), "+v"(b));
}
__device__ __forceinline__ f32x16 zero16() {
  f32x16 z;
#pragma unroll
  for (int i = 0; i < 16; ++i) z[i] = 0.f;
  return z;
}

typedef const __attribute__((address_space(1))) unsigned int* as1_u32p;
typedef __attribute__((address_space(3))) unsigned int* as3_u32p;

// 16B direct global->LDS. LDS dest: wave-uniform base + lane*16. Global src: per-lane.
__device__ __forceinline__ void gload16(const void* g, void* l) {
  __builtin_amdgcn_global_load_lds((as1_u32p)g, (as3_u32p)l, 16, 0, 0);
}

// ---------------- fp32 -> bf16 convert ----------------
__global__ void cvt_f32_bf16(const float* __restrict__ src,
                             unsigned short* __restrict__ dst, int n4) {
  int i = blockIdx.x * blockDim.x + threadIdx.x;
  int stride = gridDim.x * blockDim.x;
  for (; i < n4; i += stride) {
    float4 v = ((const float4*)src)[i];
    ushort4 o;
    o.x = f2bf(v.x); o.y = f2bf(v.y); o.z = f2bf(v.z); o.w = f2bf(v.w);
    ((ushort4*)dst)[i] = o;
  }
}

// 4 weight matrices in one launch (grid.y selects matrix)
__global__ void cvt_w4(const float* __restrict__ s0, const float* __restrict__ s1,
                       const float* __restrict__ s2, const float* __restrict__ s3,
                       unsigned short* __restrict__ d0, unsigned short* __restrict__ d1,
                       unsigned short* __restrict__ d2, unsigned short* __restrict__ d3,
                       int n4) {
  const float* src = (blockIdx.y == 0) ? s0 : (blockIdx.y == 1) ? s1 : (blockIdx.y == 2) ? s2 : s3;
  unsigned short* dst = (blockIdx.y == 0) ? d0 : (blockIdx.y == 1) ? d1 : (blockIdx.y == 2) ? d2 : d3;
  int i = blockIdx.x * blockDim.x + threadIdx.x;
  int stride = gridDim.x * blockDim.x;
  for (; i < n4; i += stride) {
    float4 v = ((const float4*)src)[i];
    ushort4 o;
    o.x = f2bf(v.x); o.y = f2bf(v.y); o.z = f2bf(v.z); o.w = f2bf(v.w);
    ((ushort4*)dst)[i] = o;
  }
}

// ---------------- shared GEMM mainloop: C(128x128) = A(128,K) * B(128,K)^T ----------------
__device__ __forceinline__ void gemm_tile_mainloop(
    const unsigned short* __restrict__ A, const unsigned short* __restrict__ Bw,
    int rowBase, int colBase,
    unsigned short* As, unsigned short* Bs,
    f32x4 acc[4][4], int tid)
{
  const int wid = tid >> 6, lane = tid & 63;
  const int wm = wid >> 1, wn = wid & 1;
  const unsigned short* Atile = A + (size_t)rowBase * DM;
  const unsigned short* Btile = Bw + (size_t)colBase * DM;

  for (int k0 = 0; k0 < DM; k0 += 64) {
#pragma unroll
    for (int j = 0; j < 4; ++j) {
      int c = j * 256 + tid;
      int row = c >> 3;
      int inB = (c & 7) * 16;
      int srcE = row * DM + k0 + ((inB ^ ((row & 7) << 4)) >> 1);
      gload16(Atile + srcE, As + (size_t)(j * 256 + wid * 64) * 8);
    }
#pragma unroll
    for (int j = 0; j < 4; ++j) {
      int c = j * 256 + tid;
      int row = c >> 3;
      int inB = (c & 7) * 16;
      int srcE = row * DM + k0 + ((inB ^ ((row & 7) << 4)) >> 1);
      gload16(Btile + srcE, Bs + (size_t)(j * 256 + wid * 64) * 8);
    }
    __syncthreads();

#pragma unroll
    for (int s2 = 0; s2 < 2; ++s2) {
      bf16x8 af[4], bfv[4];
#pragma unroll
      for (int m = 0; m < 4; ++m) {
        int row = wm * 64 + m * 16 + (lane & 15);
        int off = row * 128 + ((s2 * 64 + ((lane >> 4) * 16)) ^ ((row & 7) << 4));
        af[m] = *(const bf16x8*)((const char*)As + off);
      }
#pragma unroll
      for (int n = 0; n < 4; ++n) {
        int row = wn * 64 + n * 16 + (lane & 15);
        int off = row * 128 + ((s2 * 64 + ((lane >> 4) * 16)) ^ ((row & 7) << 4));
        bfv[n] = *(const bf16x8*)((const char*)Bs + off);
      }
#pragma unroll
      for (int m = 0; m < 4; ++m)
#pragma unroll
        for (int n = 0; n < 4; ++n)
          acc[m][n] = mfma_bf16(af[m], bfv[n], acc[m][n]);
    }
    __syncthreads();
  }
}

// ---------------- QKV projection: writes Q/K/V in [B,H,S,HD] bf16 ----------------
__global__ __launch_bounds__(256, 2) void gemm_qkv(
    const unsigned short* __restrict__ xb,
    const unsigned short* __restrict__ Wqb, const unsigned short* __restrict__ Wkb,
    const unsigned short* __restrict__ Wvb,
    unsigned short* __restrict__ Qd, unsigned short* __restrict__ Kd,
    unsigned short* __restrict__ Vd)
{
  __shared__ unsigned short As[128 * 64];
  __shared__ unsigned short Bs[128 * 64];
  const int tid = threadIdx.x;
  const int z = blockIdx.z;
  const unsigned short* W = (z == 0) ? Wqb : (z == 1) ? Wkb : Wvb;
  unsigned short* dst = (z == 0) ? Qd : (z == 1) ? Kd : Vd;
  const int rowBase = blockIdx.x * 128, colBase = blockIdx.y * 128;

  f32x4 acc[4][4];
#pragma unroll
  for (int m = 0; m < 4; ++m)
#pragma unroll
    for (int n = 0; n < 4; ++n) acc[m][n] = (f32x4){0.f, 0.f, 0.f, 0.f};

  gemm_tile_mainloop(xb, W, rowBase, colBase, As, Bs, acc, tid);

  const int wid = tid >> 6, lane = tid & 63;
  const int wm = wid >> 1, wn = wid & 1;
#pragma unroll
  for (int m = 0; m < 4; ++m)
#pragma unroll
    for (int n = 0; n < 4; ++n)
#pragma unroll
      for (int r = 0; r < 4; ++r) {
        int grow = rowBase + wm * 64 + m * 16 + ((lane >> 4) * 4) + r;  // b*SEQ+s
        int gcol = colBase + wn * 64 + n * 16 + (lane & 15);            // h*64+hd
        int b = grow >> 11, s = grow & (SEQ - 1);
        int h = gcol >> 6, hd = gcol & 63;
        dst[(((size_t)(b * NH + h)) * SEQ + s) * HDIM + hd] = f2bf(acc[m][n][r]);
      }
}

// ---------------- output projection: out = ctx @ Wo^T + bo (fp32 out) ----------------
__global__ __launch_bounds__(256, 2) void gemm_out(
    const unsigned short* __restrict__ ctx, const unsigned short* __restrict__ Wob,
    const float* __restrict__ bo, float* __restrict__ out)
{
  __shared__ unsigned short As[128 * 64];
  __shared__ unsigned short Bs[128 * 64];
  const int tid = threadIdx.x;
  const int rowBase = blockIdx.x * 128, colBase = blockIdx.y * 128;

  f32x4 acc[4][4];
#pragma unroll
  for (int m = 0; m < 4; ++m)
#pragma unroll
    for (int n = 0; n < 4; ++n) acc[m][n] = (f32x4){0.f, 0.f, 0.f, 0.f};

  gemm_tile_mainloop(ctx, Wob, rowBase, colBase, As, Bs, acc, tid);

  const int wid = tid >> 6, lane = tid & 63;
  const int wm = wid >> 1, wn = wid & 1;
#pragma unroll
  for (int m = 0; m < 4; ++m)
#pragma unroll
    for (int n = 0; n < 4; ++n)
#pragma unroll
      for (int r = 0; r < 4; ++r) {
        int grow = rowBase + wm * 64 + m * 16 + ((lane >> 4) * 4) + r;
        int gcol = colBase + wn * 64 + n * 16 + (lane & 15);
        out[(size_t)grow * DM + gcol] = acc[m][n][r] + bo[gcol];
      }
}

// ---------------- V transpose: [B,H,S,HD] -> [B,H,HD,S] ----------------
__global__ void transpose_v(const unsigned short* __restrict__ Vd,
                            unsigned short* __restrict__ VT)
{
  __shared__ unsigned short tile[64 * 72];   // [s][d], pad 72
  const int tid = threadIdx.x;
  const int bh = blockIdx.y, s0 = blockIdx.x * 64;
  const unsigned short* src = Vd + (size_t)bh * SEQ * HDIM + (size_t)s0 * HDIM;
#pragma unroll
  for (int j = 0; j < 2; ++j) {
    int c = j * 256 + tid;
    int r = c >> 3, c0 = (c & 7) * 8;
    *(u16x8*)(tile + r * 72 + c0) = *(const u16x8*)(src + r * HDIM + c0);
  }
  __syncthreads();
  unsigned short* dst = VT + (size_t)bh * HDIM * SEQ + s0;
#pragma unroll
  for (int j = 0; j < 2; ++j) {
    int c = j * 256 + tid;
    int d = c >> 3, c0 = (c & 7) * 8;
    u16x8 v;
#pragma unroll
    for (int e = 0; e < 8; ++e) v[e] = tile[(c0 + e) * 72 + d];
    *(u16x8*)(dst + (size_t)d * SEQ + c0) = v;
  }
}

// ---------------- causal flash attention, paired q-blocks + counted-vmcnt pipeline ----
// grid (8, 64). Block processes qb = blockIdx.x and qb = 15-blockIdx.x sequentially
// (uniform 34 KV-tiles/block -> no straggler tail). 4 warps x 32 q-rows.
// K/V triple-buffered in LDS; prefetch depth 2; s_waitcnt vmcnt(4) BEFORE s_barrier
// (wait-then-barrier: own stores drained pre-barrier, newer prefetch stays in flight).
__global__ __launch_bounds__(256, 2) void attn_fwd3(
    const unsigned short* __restrict__ Qg, const unsigned short* __restrict__ Kg,
    const unsigned short* __restrict__ VTg, unsigned short* __restrict__ ctx)
{
  __shared__ unsigned short smem[24576];  // 48KB: K bufs [0,12288), V^T bufs [12288,24576)

  const int tid = threadIdx.x, wid = tid >> 6, lane = tid & 63;
  const int hi = lane >> 5, lq = lane & 31;
  const int bh = blockIdx.y;
  const unsigned short* Qp = Qg  + (size_t)bh * SEQ * HDIM;
  const unsigned short* Kp = Kg  + (size_t)bh * SEQ * HDIM;
  const unsigned short* Vp = VTg + (size_t)bh * HDIM * SEQ;   // [d][s]
  const int b = bh >> 4, h = bh & 15;

  auto stageK = [&](int t, int buf) {
#pragma unroll
    for (int j = 0; j < 2; ++j) {
      int c = j * 256 + tid;
      int row = c >> 3, inB = (c & 7) * 16;
      gload16(Kp + (size_t)(t * 64 + row) * HDIM + ((inB ^ ((row & 7) << 4)) >> 1),
              smem + buf * 4096 + (size_t)(j * 256 + wid * 64) * 8);
    }
  };
  auto stageV = [&](int t, int buf) {
#pragma unroll
    for (int j = 0; j < 2; ++j) {
      int c = j * 256 + tid;
      int row = c >> 3, inB = (c & 7) * 16;   // row = d
      gload16(Vp + (size_t)row * SEQ + t * 64 + ((inB ^ ((row & 7) << 4)) >> 1),
              smem + 12288 + buf * 4096 + (size_t)(j * 256 + wid * 64) * 8);
    }
  };

  for (int half = 0; half < 2; ++half) {
    const int qb = half == 0 ? (int)blockIdx.x : (NQB - 1 - (int)blockIdx.x);
    const int qw0 = qb * 128 + wid * 32;       // warp's first q row

    // Q B-frags: lane q=lq, d = ks*16 + hi*8 + j
    bf16x8 qf[4];
    {
      const unsigned short* qrow = Qp + (size_t)(qw0 + lq) * HDIM + hi * 8;
#pragma unroll
      for (int ks = 0; ks < 4; ++ks) qf[ks] = *(const bf16x8*)(qrow + ks * 16);
    }

    f32x16 o0 = zero16(), o1 = zero16();
    float m_run = -INFINITY, l_run = 0.f;
    const int nt = 2 * qb + 2;

    // prologue: stage tiles 0,1 (nt >= 2 always)
    stageK(0, 0); stageV(0, 0);
    stageK(1, 1); stageV(1, 1);
    asm volatile("s_waitcnt vmcnt(4)" ::: "memory");
    __builtin_amdgcn_s_barrier();

    for (int t = 0; t < nt; ++t) {
      const int cur = t % 3;
      const bool pf = (t + 2) < nt;
      if (pf) { int nb = (t + 2) % 3; stageK(t + 2, nb); stageV(t + 2, nb); }

      if (t * 64 <= qw0 + 31) {   // warp has at least one visible key in this tile
        // ---- QK^T: S^T[64 key][32 q], lane owns q=lq; keys split lane<->lane+32 ----
        const unsigned short* Kl = smem + cur * 4096;
        f32x16 s0 = zero16(), s1 = zero16();
        __builtin_amdgcn_s_setprio(1);
#pragma unroll
        for (int ks = 0; ks < 4; ++ks) {
          int r0 = lq, r1 = lq + 32;
          int col = (ks * 32 + hi * 16);
          bf16x8 a0 = *(const bf16x8*)((const char*)Kl + r0 * 128 + (col ^ ((r0 & 7) << 4)));
          bf16x8 a1 = *(const bf16x8*)((const char*)Kl + r1 * 128 + (col ^ ((r1 & 7) << 4)));
          s0 = mfma32(a0, qf[ks], s0);
          s1 = mfma32(a1, qf[ks], s1);
        }
        __builtin_amdgcn_s_setprio(0);

        // ---- causal mask (raw scores; 1/8 scale folded into exp) ----
        if (t * 64 + 63 > qw0) {
          const int q = qw0 + lq;
          const int kb = t * 64 + 4 * hi;
#pragma unroll
          for (int r = 0; r < 16; ++r) {
            int k0 = kb + (r & 3) + 8 * (r >> 2);
            if (k0 > q)      s0[r] = -INFINITY;
            if (k0 + 32 > q) s1[r] = -INFINITY;
          }
        }

        // ---- online softmax, lane-local + 1 cross-half exchange ----
        float pmax = s0[0];
#pragma unroll
        for (int r = 1; r < 16; ++r) pmax = fmaxf(pmax, s0[r]);
#pragma unroll
        for (int r = 0; r < 16; ++r) pmax = fmaxf(pmax, s1[r]);
        pmax = fmaxf(pmax, __shfl_xor(pmax, 32, 64));

        if (!__all(pmax - m_run <= 64.0f)) {     // defer-max THR: e^(64*0.125)=e^8
          float mn = fmaxf(m_run, pmax);
          float alpha = __expf((m_run - mn) * 0.125f);
          l_run *= alpha;
#pragma unroll
          for (int r = 0; r < 16; ++r) { o0[r] *= alpha; o1[r] *= alpha; }
          m_run = mn;
        }

        float rsum = 0.f;
#pragma unroll
        for (int r = 0; r < 16; ++r) {
          s0[r] = __expf((s0[r] - m_run) * 0.125f); rsum += s0[r];
        }
#pragma unroll
        for (int r = 0; r < 16; ++r) {
          s1[r] = __expf((s1[r] - m_run) * 0.125f); rsum += s1[r];
        }
        rsum += __shfl_xor(rsum, 32, 64);
        l_run += rsum;

        // ---- P -> bf16 B-frags via cvt_pk + permlane32_swap (T12) ----
        bf16x8 pfr[4];
#pragma unroll
        for (int h2 = 0; h2 < 2; ++h2) {
          {
            unsigned va = cvtpk(s0[h2 * 8 + 0], s0[h2 * 8 + 1]);
            unsigned vb = cvtpk(s0[h2 * 8 + 4], s0[h2 * 8 + 5]);
            unsigned vc = cvtpk(s0[h2 * 8 + 2], s0[h2 * 8 + 3]);
            unsigned vd = cvtpk(s0[h2 * 8 + 6], s0[h2 * 8 + 7]);
            permswap(va, vb); permswap(vc, vd);
            u32x4 tt; tt.x = va; tt.y = vc; tt.z = vb; tt.w = vd;
            pfr[h2] = __builtin_bit_cast(bf16x8, tt);
          }
          {
            unsigned va = cvtpk(s1[h2 * 8 + 0], s1[h2 * 8 + 1]);
            unsigned vb = cvtpk(s1[h2 * 8 + 4], s1[h2 * 8 + 5]);
            unsigned vc = cvtpk(s1[h2 * 8 + 2], s1[h2 * 8 + 3]);
            unsigned vd = cvtpk(s1[h2 * 8 + 6], s1[h2 * 8 + 7]);
            permswap(va, vb); permswap(vc, vd);
            u32x4 tt; tt.x = va; tt.y = vc; tt.z = vb; tt.w = vd;
            pfr[2 + h2] = __builtin_bit_cast(bf16x8, tt);
          }
        }

        // ---- PV: O^T[64 d][32 q] += V^T * P^T ----
        const unsigned short* Vl = smem + 12288 + cur * 4096;
        __builtin_amdgcn_s_setprio(1);
#pragma unroll
        for (int ks = 0; ks < 4; ++ks) {
          int r0 = lq, r1 = lq + 32;   // d rows
          int col = (ks * 32 + hi * 16);
          bf16x8 va0 = *(const bf16x8*)((const char*)Vl + r0 * 128 + (col ^ ((r0 & 7) << 4)));
          bf16x8 va1 = *(const bf16x8*)((const char*)Vl + r1 * 128 + (col ^ ((r1 & 7) << 4)));
          o0 = mfma32(va0, pfr[ks], o0);
          o1 = mfma32(va1, pfr[ks], o1);
        }
        __builtin_amdgcn_s_setprio(0);
      }

      // wait-then-barrier: own tile-(t+1) stores drained; tile-(t+2) stays in flight
      if (pf) asm volatile("s_waitcnt vmcnt(4)" ::: "memory");
      else    asm volatile("s_waitcnt vmcnt(0)" ::: "memory");
      __builtin_amdgcn_s_barrier();
    }

    // ---- epilogue: normalize, bounce through LDS, coalesced store [B,S,D] ----
    const float invl = 1.0f / l_run;
    unsigned short* Ot = smem;            // [128 q][64 d] bf16, XOR-swizzled rows
    const int q = wid * 32 + lq;
#pragma unroll
    for (int r2 = 0; r2 < 16; r2 += 2) {
      int d = (r2 & 3) + 8 * (r2 >> 2) + 4 * hi;
      unsigned w0 = cvtpk(o0[r2] * invl, o0[r2 + 1] * invl);
      *(unsigned*)((char*)Ot + q * 128 + ((2 * d) ^ ((q & 7) << 4))) = w0;
      int d2 = d + 32;
      unsigned w1 = cvtpk(o1[r2] * invl, o1[r2 + 1] * invl);
      *(unsigned*)((char*)Ot + q * 128 + ((2 * d2) ^ ((q & 7) << 4))) = w1;
    }
    __syncthreads();

#pragma unroll
    for (int i = 0; i < 4; ++i) {
      int idx = i * 256 + tid;
      int qq = idx >> 3, c16 = (idx & 7) * 8;
      bf16x8 v = *(const bf16x8*)((const char*)Ot + qq * 128 + ((2 * c16) ^ ((qq & 7) << 4)));
      *(bf16x8*)(ctx + ((size_t)(b * SEQ) + qb * 128 + qq) * DM + h * 64 + c16) = v;
    }
    __syncthreads();   // protect smem before next half's staging
  }
}

// ---------------- launch ----------------
extern "C" void kernel_launch(void* const* d_in, const int* in_sizes, int n_in,
                              void* d_out, int out_size, void* d_ws, size_t ws_size,
                              hipStream_t stream)
{
  (void)in_sizes; (void)n_in; (void)out_size; (void)ws_size;
  const float* x  = (const float*)d_in[0];
  const float* Wq = (const float*)d_in[1];
  const float* Wk = (const float*)d_in[2];
  const float* Wv = (const float*)d_in[3];
  const float* Wo = (const float*)d_in[4];
  const float* bo = (const float*)d_in[5];
  float* out = (float*)d_out;

  char* ws = (char*)d_ws;
  unsigned short* xb  = (unsigned short*)(ws);                        // 16 MiB (x bf16; reused as V^T)
  unsigned short* Wqb = (unsigned short*)(ws + (size_t)16 * 1048576);
  unsigned short* Wkb = (unsigned short*)(ws + (size_t)18 * 1048576);
  unsigned short* Wvb = (unsigned short*)(ws + (size_t)20 * 1048576);
  unsigned short* Wob = (unsigned short*)(ws + (size_t)22 * 1048576);
  unsigned short* Qd  = (unsigned short*)(ws + (size_t)24 * 1048576); // [B,H,S,HD]
  unsigned short* Kd  = (unsigned short*)(ws + (size_t)40 * 1048576);
  unsigned short* Vd  = (unsigned short*)(ws + (size_t)56 * 1048576);
  unsigned short* ctxb= (unsigned short*)(ws + (size_t)72 * 1048576); // [B,S,D]
  unsigned short* VT  = xb;                                           // [B,H,HD,S] (x dead after gemm_qkv)

  cvt_f32_bf16<<<2048, 256, 0, stream>>>(x, xb, MROWS * DM / 4);
  cvt_w4<<<dim3(64, 4), 256, 0, stream>>>(Wq, Wk, Wv, Wo, Wqb, Wkb, Wvb, Wob, DM * DM / 4);

  gemm_qkv<<<dim3(MROWS / 128, DM / 128, 3), 256, 0, stream>>>(xb, Wqb, Wkb, Wvb, Qd, Kd, Vd);
  transpose_v<<<dim3(SEQ / 64, BATCH * NH), 256, 0, stream>>>(Vd, VT);
  attn_fwd3<<<dim3(NQB / 2, BATCH * NH), 256, 0, stream>>>(Qd, Kd, VT, ctxb);
  gemm_out<<<dim3(MROWS / 128, DM / 128, 1), 256, 0, stream>>>(ctxb, Wob, bo, out);
}